// Round 20
// baseline (122.594 us; speedup 1.0000x reference)
//
#include <hip/hip_runtime.h>
#include <cstdint>

// ---------------------------------------------------------------------------
// LoRA MHA: B=4,S=1024,E=1024,H=16,D=64,R=16.  bf16 MFMA, fp32 accum.
// LoRA folded into the weights: W' = W + B@A (scale=1).
// R20: R19 base (121.46us) + attn 2-tile unrolled iteration: 4 LDS buffers,
// 8 iterations of {vmcnt(0); lgkm(0); barrier; STAGE pair (tiles 2it+2,
// 2it+3); compute tile 2it; compute tile 2it+1}.  Barriers halve (16->8)
// and stages get a full-iteration (~1200cy) lead before consumption.
// qkv (8-phase 256x192), gemm_o (p3+XCD remap), prep unchanged.
// ---------------------------------------------------------------------------

typedef __attribute__((ext_vector_type(8))) short bf16x8;
typedef __attribute__((ext_vector_type(4))) float f32x4;
typedef __attribute__((ext_vector_type(16))) float f32x16;
typedef __attribute__((ext_vector_type(4))) unsigned short u16x4;
typedef __attribute__((ext_vector_type(4))) unsigned int u32x4;

__device__ __forceinline__ short f2bf(float f) {
  unsigned u = __builtin_bit_cast(unsigned, f);
  u += 0x7FFFu + ((u >> 16) & 1u);          // RNE
  return (short)(u >> 16);
}

typedef __attribute__((address_space(1))) const unsigned int as1_uint;
typedef __attribute__((address_space(3))) unsigned int as3_uint;

__device__ __forceinline__ void gload_lds16(const short* g, const short* l) {
  __builtin_amdgcn_global_load_lds((as1_uint*)g,
      (as3_uint*)(unsigned int)(uintptr_t)l, 16, 0, 0);
}

__device__ __forceinline__ unsigned cvtpk(float lo, float hi) {
  unsigned r;
  asm("v_cvt_pk_bf16_f32 %0, %1, %2" : "=v"(r) : "v"(lo), "v"(hi));
  return r;
}
__device__ __forceinline__ void plswap(unsigned &a, unsigned &b) {
  asm("v_permlane32_swap_b32 %0, %1" : "+v"(a), "+v"(b));
}

__device__ __forceinline__ void build_pfrag(const f32x16 &s, bf16x8 &f0, bf16x8 &f1) {
  unsigned x0 = cvtpk(s[0], s[1]),  x1 = cvtpk(s[2], s[3]);
  unsigned x2 = cvtpk(s[4], s[5]),  x3 = cvtpk(s[6], s[7]);
  plswap(x0, x2); plswap(x1, x3);
  unsigned y0 = cvtpk(s[8], s[9]),  y1 = cvtpk(s[10], s[11]);
  unsigned y2 = cvtpk(s[12], s[13]), y3 = cvtpk(s[14], s[15]);
  plswap(y0, y2); plswap(y1, y3);
  u32x4 a = {x0, x1, x2, x3}, b = {y0, y1, y2, y3};
  f0 = __builtin_bit_cast(bf16x8, a);
  f1 = __builtin_bit_cast(bf16x8, b);
}

// ---------------------------------------------------------------------------
// Kernel 1: fused prep.  Blocks [0,4096): cast x fp32 -> bf16 [4096][1024].
// Blocks [4096,8192): fold LoRA, W'[p] = W_p + B_p@A_p (fp32 -> bf16).
// ---------------------------------------------------------------------------
__global__ void prep_kernel(const float* __restrict__ x, short* __restrict__ xb,
                            const float* __restrict__ wq, const float* __restrict__ wk,
                            const float* __restrict__ wv, const float* __restrict__ wo,
                            const float* __restrict__ bq, const float* __restrict__ bk,
                            const float* __restrict__ bv, const float* __restrict__ bo,
                            const float* __restrict__ aq, const float* __restrict__ ak,
                            const float* __restrict__ av, const float* __restrict__ ao,
                            short* __restrict__ wbo) {
  const int b = blockIdx.x;
  if (b < 4096) {
    const int idx = b * 256 + threadIdx.x;
    f32x4 v = ((const f32x4*)x)[idx];
    u16x4 o;
    o[0] = (unsigned short)f2bf(v[0]);
    o[1] = (unsigned short)f2bf(v[1]);
    o[2] = (unsigned short)f2bf(v[2]);
    o[3] = (unsigned short)f2bf(v[3]);
    ((u16x4*)xb)[idx] = o;
  } else {
    const int bb = b - 4096;
    const int p = bb >> 10;
    const float* W  = (p == 0) ? wq : (p == 1) ? wk : (p == 2) ? wv : wo;
    const float* Bm = (p == 0) ? bq : (p == 1) ? bk : (p == 2) ? bv : bo;
    const float* A  = (p == 0) ? aq : (p == 1) ? ak : (p == 2) ? av : ao;
    const int idx = (bb & 1023) * 256 + threadIdx.x;
    const int n = idx >> 8;
    const int e4 = idx & 255;
    f32x4 acc = ((const f32x4*)(W + (size_t)n * 1024))[e4];
    const float* br = Bm + n * 16;
    #pragma unroll
    for (int r = 0; r < 16; ++r) {
      const f32x4 a4 = ((const f32x4*)(A + (size_t)r * 1024))[e4];
      const float bl = br[r];
      acc[0] += bl * a4[0];
      acc[1] += bl * a4[1];
      acc[2] += bl * a4[2];
      acc[3] += bl * a4[3];
    }
    u16x4 o;
    o[0] = (unsigned short)f2bf(acc[0]);
    o[1] = (unsigned short)f2bf(acc[1]);
    o[2] = (unsigned short)f2bf(acc[2]);
    o[3] = (unsigned short)f2bf(acc[3]);
    *(u16x4*)(wbo + (size_t)p * 1048576 + (size_t)idx * 4) = o;
  }
}

// ---------------------------------------------------------------------------
// Kernel 2: merged q/k/v projection, 256x192 tile, 8 waves (2M x 4N),
// 8-phase counted-vmcnt schedule.  Grid 256 = 16 brow x 16 bcol (100% CU
// fill), XCD swizzle (2 brows x 16 bcols per XCD).  (unchanged from R18)
// ---------------------------------------------------------------------------
__global__ __launch_bounds__(512, 1)
void gemm_qkv(const short* __restrict__ xb, const short* __restrict__ wb,
              const float* __restrict__ biasq, const float* __restrict__ biask,
              const float* __restrict__ biasv,
              short* __restrict__ qbuf, short* __restrict__ kbuf, short* __restrict__ vtb) {
  __shared__ short Ah[2][2][8192];     // [buf][half][128 rows * 64 cols]
  __shared__ short Bf[2][12288];       // [buf][192 rows * 64 cols]
  const int wg = blockIdx.x;                    // 0..255
  const int swz = (wg & 7) * 32 + (wg >> 3);    // XCD owns 2 brows x 16 bcols
  const int brow = swz >> 4, bcol = swz & 15;
  const int tid = threadIdx.x;
  const int wid = tid >> 6, lane = tid & 63;
  const int wr = wid >> 2, wc = wid & 3;        // 2M x 4N wave grid
  const int lrow = lane & 15, lk = lane >> 4;
  const int sl8 = (tid & 7) ^ ((tid >> 3) & 7); // inverse-swizzled source slot

  const short* Asrc = xb + (size_t)brow * 256 * 1024;
  const short* Bsrc = wb + (size_t)bcol * 192 * 1024;

#define STAGE_A(hf, kt, buf)                                                   \
  { _Pragma("unroll")                                                          \
    for (int i = 0; i < 2; ++i) {                                              \
      const int row = (hf) * 128 + i * 64 + (tid >> 3);                        \
      gload_lds16(Asrc + (size_t)row * 1024 + (kt) * 64 + sl8 * 8,             \
                  Ah[buf][hf] + (i * 64 + wid * 8) * 64);                      \
    } }
#define STAGE_B(ch, kt, buf)                                                   \
  {                                                                            \
    const int row = (ch) * 64 + (tid >> 3);                                    \
    gload_lds16(Bsrc + (size_t)row * 1024 + (kt) * 64 + sl8 * 8,               \
                Bf[buf] + (ch) * 4096 + tid * 8);                              \
  }

  const f32x4 fz = {0.f, 0.f, 0.f, 0.f};
  f32x4 acc[8][3];
  #pragma unroll
  for (int a = 0; a < 8; ++a)
    #pragma unroll
    for (int b = 0; b < 3; ++b) acc[a][b] = fz;

  STAGE_A(0, 0, 0)
  STAGE_A(1, 0, 0)
  STAGE_B(0, 0, 0) STAGE_B(1, 0, 0) STAGE_B(2, 0, 0)
  STAGE_B(0, 1, 1) STAGE_B(1, 1, 1) STAGE_B(2, 1, 1)
  asm volatile("s_waitcnt vmcnt(3)" ::: "memory");
  __builtin_amdgcn_s_barrier();

  for (int t = 0; t < 16; ++t) {
    const int cur = t & 1;
    bf16x8 bfr[3][2];
    #pragma unroll
    for (int q = 0; q < 4; ++q) {
      if (q == 0) {
        #pragma unroll
        for (int nj = 0; nj < 3; ++nj) {
          const int rr = wc * 48 + nj * 16 + lrow;
          #pragma unroll
          for (int kc = 0; kc < 2; ++kc)
            bfr[nj][kc] = *(const bf16x8*)(&Bf[cur][rr * 64 + (((kc * 4 + lk) ^ (rr & 7)) * 8)]);
        }
      }
      bf16x8 afr[2][2];
      #pragma unroll
      for (int m2 = 0; m2 < 2; ++m2) {
        const int rr = q * 32 + m2 * 16 + lrow;
        #pragma unroll
        for (int kc = 0; kc < 2; ++kc)
          afr[m2][kc] = *(const bf16x8*)(&Ah[cur][wr][rr * 64 + (((kc * 4 + lk) ^ (rr & 7)) * 8)]);
      }
      if (q == 0)      { if (t + 1 < 16) STAGE_A(0, t + 1, cur ^ 1) }
      else if (q == 1) { if (t + 1 < 16) STAGE_A(1, t + 1, cur ^ 1) }
      else if (q == 2) { if (t + 2 < 16) { STAGE_B(0, t + 2, cur) STAGE_B(1, t + 2, cur) } }
      else             { if (t + 2 < 16) STAGE_B(2, t + 2, cur) }

      if (q == 0) asm volatile("s_waitcnt lgkmcnt(6)" ::: "memory");
      __builtin_amdgcn_s_barrier();
      asm volatile("s_waitcnt lgkmcnt(0)" ::: "memory");
      __builtin_amdgcn_s_setprio(1);
      #pragma unroll
      for (int kc = 0; kc < 2; ++kc)
        #pragma unroll
        for (int m2 = 0; m2 < 2; ++m2)
          #pragma unroll
          for (int nj = 0; nj < 3; ++nj)
            acc[q * 2 + m2][nj] = __builtin_amdgcn_mfma_f32_16x16x32_bf16(
                afr[m2][kc], bfr[nj][kc], acc[q * 2 + m2][nj], 0, 0, 0);
      __builtin_amdgcn_s_setprio(0);
      if (q == 3) {
        if (t < 14) asm volatile("s_waitcnt vmcnt(3)" ::: "memory");
        else        asm volatile("s_waitcnt vmcnt(0)" ::: "memory");
      }
      __builtin_amdgcn_s_barrier();
    }
  }
#undef STAGE_A
#undef STAGE_B

  const float SCALE = 0.18033688f;   // log2(e)/8 folded into q
  #pragma unroll
  for (int mi = 0; mi < 8; ++mi) {
    #pragma unroll
    for (int r = 0; r < 4; ++r) {
      const int gr = brow * 256 + wr * 128 + mi * 16 + lk * 4 + r;   // C/D row
      const int bb = gr >> 10, s = gr & 1023;
      #pragma unroll
      for (int nj = 0; nj < 3; ++nj) {
        const int gc = bcol * 192 + wc * 48 + nj * 16 + lrow;        // 0..3071
        const int p = gc >> 10, pc = gc & 1023;
        const float bv = ((p == 0) ? biasq : (p == 1) ? biask : biasv)[pc];
        const float v = (acc[mi][nj][r] + bv) * ((p == 0) ? SCALE : 1.0f);
        const int h = pc >> 6, d = pc & 63;
        const int bh = bb * 16 + h;
        if (p == 2)
          vtb[((size_t)bh * 64 + d) * 1024 + s] = f2bf(v);
        else
          ((p == 0) ? qbuf : kbuf)[((size_t)bh * 1024 + s) * 64 + d] = f2bf(v);
      }
    }
  }
}

// ---------------------------------------------------------------------------
// Kernel 3: flash attention, swapped 32x32 MFMA form.
// 8-wave blocks (512 thr, 256 q-rows), grid (64 bh, 4 qt) = 256 blocks.
// 2-tile unrolled iterations, 4-buffer LDS ring: per iteration
// {vmcnt(0); lgkm(0); barrier; STAGE tiles 2it+2,2it+3; compute 2it, 2it+1}.
// Stages get a full-iteration lead; barriers halve (16 -> 8).
// ---------------------------------------------------------------------------
__global__ __launch_bounds__(512)
void attn_kernel(const short* __restrict__ qbuf, const short* __restrict__ kbuf,
                 const short* __restrict__ vtb, short* __restrict__ cb) {
  __shared__ short Ks[4][64 * 64];
  __shared__ short Vs[4][64 * 64];
  const int bh = blockIdx.x, qt = blockIdx.y;
  const int tid = threadIdx.x, w = tid >> 6, lane = tid & 63;
  const int l31 = lane & 31, hi = lane >> 5;
  const int srow = lane >> 3, sphys = lane & 7;
  const short* Qp = qbuf + (size_t)bh * 65536;
  const short* Kp = kbuf + (size_t)bh * 65536;
  const short* Vp = vtb + (size_t)bh * 65536;
  const int q0 = qt * 256 + w * 32;

  bf16x8 bq[4];
  #pragma unroll
  for (int kc = 0; kc < 4; ++kc)
    bq[kc] = *(const bf16x8*)(Qp + (size_t)(q0 + l31) * 64 + kc * 16 + hi * 8);

  const f32x16 fz16 = {0.f,0.f,0.f,0.f,0.f,0.f,0.f,0.f,0.f,0.f,0.f,0.f,0.f,0.f,0.f,0.f};
  float m_run = -1e30f, l_run = 0.f;
  f32x16 acc0 = fz16, acc1 = fz16;

  // stage one K/V tile into buffer buf (2 loads/thread)
  #define STAGE_KV(buf, tt)                                                  \
    {                                                                        \
      const int t0s = (tt) * 64;                                             \
      const int row = w * 8 + srow;                                          \
      const int sl = sphys ^ (row & 7);                                      \
      gload_lds16(Kp + (size_t)(t0s + row) * 64 + sl * 8, Ks[buf] + w * 512); \
      gload_lds16(Vp + (size_t)row * 1024 + t0s + sl * 8, Vs[buf] + w * 512); \
    }

  // full per-tile compute (QK^T, softmax, pfrag, PV) on buffer bix
  #define TILE_COMPUTE(bix)                                                  \
  {                                                                          \
    f32x16 s0 = fz16, s1 = fz16;                                             \
    __builtin_amdgcn_s_setprio(1);                                           \
    _Pragma("unroll")                                                        \
    for (int kc = 0; kc < 4; ++kc) {                                         \
      const int slot = (kc * 2 + hi) ^ (l31 & 7);                            \
      const bf16x8 ak0 = *(const bf16x8*)(Ks[bix] + l31 * 64 + slot * 8);    \
      const bf16x8 ak1 = *(const bf16x8*)(Ks[bix] + (32 + l31) * 64 + slot * 8); \
      s0 = __builtin_amdgcn_mfma_f32_32x32x16_bf16(ak0, bq[kc], s0, 0, 0, 0);\
      s1 = __builtin_amdgcn_mfma_f32_32x32x16_bf16(ak1, bq[kc], s1, 0, 0, 0);\
    }                                                                        \
    __builtin_amdgcn_s_setprio(0);                                           \
    float t16[16];                                                           \
    _Pragma("unroll")                                                        \
    for (int r = 0; r < 8; ++r) t16[r] = fmaxf(s0[2 * r], s0[2 * r + 1]);    \
    _Pragma("unroll")                                                        \
    for (int r = 0; r < 8; ++r) t16[8 + r] = fmaxf(s1[2 * r], s1[2 * r + 1]);\
    _Pragma("unroll")                                                        \
    for (int r = 0; r < 8; ++r) t16[r] = fmaxf(t16[r], t16[r + 8]);          \
    _Pragma("unroll")                                                        \
    for (int r = 0; r < 4; ++r) t16[r] = fmaxf(t16[r], t16[r + 4]);          \
    float tm = fmaxf(fmaxf(t16[0], t16[1]), fmaxf(t16[2], t16[3]));          \
    tm = fmaxf(tm, __shfl_xor(tm, 32, 64));                                  \
    if (__any(tm - m_run > 8.0f)) {                                          \
      const float mn = fmaxf(m_run, tm);                                     \
      const float alpha = exp2f(m_run - mn);                                 \
      m_run = mn;                                                            \
      l_run *= alpha;                                                        \
      _Pragma("unroll")                                                      \
      for (int r = 0; r < 16; ++r) { acc0[r] *= alpha; acc1[r] *= alpha; }   \
    }                                                                        \
    float a16[16];                                                           \
    _Pragma("unroll")                                                        \
    for (int r = 0; r < 16; ++r) { s0[r] = exp2f(s0[r] - m_run); }           \
    _Pragma("unroll")                                                        \
    for (int r = 0; r < 16; ++r) { s1[r] = exp2f(s1[r] - m_run); }           \
    _Pragma("unroll")                                                        \
    for (int r = 0; r < 8; ++r) a16[r] = s0[2 * r] + s0[2 * r + 1];          \
    _Pragma("unroll")                                                        \
    for (int r = 0; r < 8; ++r) a16[8 + r] = s1[2 * r] + s1[2 * r + 1];      \
    _Pragma("unroll")                                                        \
    for (int r = 0; r < 8; ++r) a16[r] += a16[r + 8];                        \
    _Pragma("unroll")                                                        \
    for (int r = 0; r < 4; ++r) a16[r] += a16[r + 4];                        \
    float rs = (a16[0] + a16[1]) + (a16[2] + a16[3]);                        \
    rs += __shfl_xor(rs, 32, 64);                                            \
    l_run += rs;                                                             \
    bf16x8 pf[4];                                                            \
    build_pfrag(s0, pf[0], pf[1]);                                           \
    build_pfrag(s1, pf[2], pf[3]);                                           \
    __builtin_amdgcn_s_setprio(1);                                           \
    _Pragma("unroll")                                                        \
    for (int kc4 = 0; kc4 < 4; ++kc4) {                                      \
      const int slot = (kc4 * 2 + hi) ^ (l31 & 7);                           \
      const bf16x8 av0 = *(const bf16x8*)(Vs[bix] + l31 * 64 + slot * 8);    \
      const bf16x8 av1 = *(const bf16x8*)(Vs[bix] + (32 + l31) * 64 + slot * 8); \
      acc0 = __builtin_amdgcn_mfma_f32_32x32x16_bf16(av0, pf[kc4], acc0, 0, 0, 0); \
      acc1 = __builtin_amdgcn_mfma_f32_32x32x16_bf16(av1, pf[kc4], acc1, 0, 0, 0); \
    }                                                                        \
    __builtin_amdgcn_s_setprio(0);                                           \
  }

  STAGE_KV(0, 0);
  STAGE_KV(1, 1);

  for (int it = 0; it < 8; ++it) {
    asm volatile("s_waitcnt vmcnt(0)" ::: "memory");     // pair 2it,2it+1 landed
    asm volatile("s_waitcnt lgkmcnt(0)" ::: "memory");   // my prev reads retired
    __builtin_amdgcn_s_barrier();                        // all waves synced
    if (it < 7) {
      STAGE_KV((2 * it + 2) & 3, 2 * it + 2);            // full-iteration lead
      STAGE_KV((2 * it + 3) & 3, 2 * it + 3);
    }
    TILE_COMPUTE((2 * it) & 3)
    TILE_COMPUTE((2 * it + 1) & 3)
  }
  #undef STAGE_KV
  #undef TILE_COMPUTE

  const int bb = bh >> 4, h = bh & 15;
  const int s = q0 + l31;
  short* crow = cb + (size_t)(bb * 1024 + s) * 1024 + h * 64;
  const float inv = 1.f / l_run;
  #pragma unroll
  for (int rp = 0; rp < 8; ++rp) {
    const int r = rp * 2;
    const int d = (r & 3) + 8 * (r >> 2) + 4 * hi;
    const unsigned p0 = (unsigned)(unsigned short)f2bf(acc0[r] * inv)
                      | ((unsigned)(unsigned short)f2bf(acc0[r + 1] * inv) << 16);
    const unsigned p1 = (unsigned)(unsigned short)f2bf(acc1[r] * inv)
                      | ((unsigned)(unsigned short)f2bf(acc1[r + 1] * inv) << 16);
    *(unsigned*)(crow + d) = p0;
    *(unsigned*)(crow + 32 + d) = p1;
  }
}

// ---------------------------------------------------------------------------
// GEMM core, depth-2 counted-vmcnt pipeline (gemm_o).
// ---------------------------------------------------------------------------
__device__ __forceinline__ void gemm_core_p3(const short* __restrict__ xrow,
                                             const short* __restrict__ wrow,
                                             short (&As)[3][8192], short (&Bs)[3][8192],
                                             f32x4 (&acc)[4][4]) {
  const int tid = threadIdx.x;
  const int wv = tid >> 6, lane = tid & 63;
  const int wr = wv >> 1, wc = wv & 1;
  const int lrow = lane & 15, lk = lane >> 4;
  const int srow = lane >> 3, sphys = lane & 7;

#define STAGE_G(buf, kt)                                                       \
  {                                                                            \
    _Pragma("unroll")                                                          \
    for (int i = 0; i < 4; ++i) {                                              \
      const int ch = i * 4 + wv;                                               \
      const int row = ch * 8 + srow;                                           \
      const int sl = sphys ^ (row & 7);                                        \
      gload_lds16(xrow + (size_t)row * 1024 + (kt) * 64 + sl * 8, As[buf] + ch * 512); \
      gload_lds16(wrow + (size_t)row * 1024 + (kt) * 64 + sl * 8, Bs[buf] + ch * 512); \
    }                                                                          \
  }

  STAGE_G(0, 0);
  STAGE_G(1, 1);
  int cur = 0;
  for (int kt = 0; kt < 16; ++kt) {
    if (kt < 14) {
      const int nb = (cur == 0) ? 2 : (cur - 1);   // (kt+2)%3
      STAGE_G(nb, kt + 2);
      asm volatile("s_waitcnt vmcnt(16)" ::: "memory");
    } else if (kt == 14) {
      asm volatile("s_waitcnt vmcnt(8)" ::: "memory");
    } else {
      asm volatile("s_waitcnt vmcnt(0)" ::: "memory");
    }
    __builtin_amdgcn_s_barrier();

    #pragma unroll
    for (int kc = 0; kc < 2; ++kc) {
      bf16x8 af[4], bw[4];
      #pragma unroll
      for (int mi = 0; mi < 4; ++mi) {
        const int row = wr * 64 + mi * 16 + lrow;
        const int slot = (kc * 4 + lk) ^ (row & 7);
        af[mi] = *(const bf16x8*)(As[cur] + row * 64 + slot * 8);
      }
      #pragma unroll
      for (int nj = 0; nj < 4; ++nj) {
        const int row = wc * 64 + nj * 16 + lrow;
        const int slot = (kc * 4 + lk) ^ (row & 7);
        bw[nj] = *(const bf16x8*)(Bs[cur] + row * 64 + slot * 8);
      }
      __builtin_amdgcn_s_setprio(1);
      #pragma unroll
      for (int mi = 0; mi < 4; ++mi)
        #pragma unroll
        for (int nj = 0; nj < 4; ++nj)
          acc[mi][nj] = __builtin_amdgcn_mfma_f32_16x16x32_bf16(af[mi], bw[nj], acc[mi][nj], 0, 0, 0);
      __builtin_amdgcn_s_setprio(0);
    }

    asm volatile("s_waitcnt lgkmcnt(0)" ::: "memory");
    __builtin_amdgcn_s_barrier();
    cur = (cur == 2) ? 0 : (cur + 1);
  }
#undef STAGE_G
}

// ---------------------------------------------------------------------------
// Kernel 4: o-projection -> fp32 d_out (p3 core).  1-D grid 256; XCD remap:
// xcd = wg&7 owns brows [4*xcd, 4*xcd+4) x all 8 bcols.
// ---------------------------------------------------------------------------
__global__ __launch_bounds__(256)
void gemm_o(const short* __restrict__ cb, const short* __restrict__ wo,
            const float* __restrict__ biaso, float* __restrict__ out) {
  __shared__ short As[3][8192];
  __shared__ short Bs[3][8192];
  const int wg = blockIdx.x;              // 0..255
  const int xcd = wg & 7, ix = wg >> 3;   // 32 blocks per XCD
  const int brow = xcd * 4 + (ix & 3);    // 4 brows per XCD
  const int bcol = ix >> 2;               // all 8 bcols
  const f32x4 fz = {0.f, 0.f, 0.f, 0.f};
  f32x4 acc[4][4];
  #pragma unroll
  for (int a = 0; a < 4; ++a)
    #pragma unroll
    for (int b = 0; b < 4; ++b) acc[a][b] = fz;

  gemm_core_p3(cb + (size_t)brow * 128 * 1024, wo + (size_t)bcol * 128 * 1024,
               As, Bs, acc);

  const int tid = threadIdx.x;
  const int wv = tid >> 6, lane = tid & 63;
  const int wr = wv >> 1, wc = wv & 1;
  const int lrow = lane & 15, lk = lane >> 4;
  float bcv[4];
  #pragma unroll
  for (int nj = 0; nj < 4; ++nj)
    bcv[nj] = biaso[bcol * 128 + wc * 64 + nj * 16 + lrow];

  #pragma unroll
  for (int mi = 0; mi < 4; ++mi) {
    #pragma unroll
    for (int r = 0; r < 4; ++r) {
      const int gr = brow * 128 + wr * 64 + mi * 16 + lk * 4 + r;
      #pragma unroll
      for (int nj = 0; nj < 4; ++nj) {
        const int gc = bcol * 128 + wc * 64 + nj * 16 + lrow;
        out[(size_t)gr * 1024 + gc] = acc[mi][nj][r] + bcv[nj];
      }
    }
  }
}

// ---------------------------------------------------------------------------
extern "C" void kernel_launch(void* const* d_in, const int* in_sizes, int n_in,
                              void* d_out, int out_size, void* d_ws, size_t ws_size,
                              hipStream_t stream) {
  (void)in_sizes; (void)n_in; (void)out_size; (void)ws_size;
  const float* x   = (const float*)d_in[0];
  const float* qw  = (const float*)d_in[1];
  const float* qb  = (const float*)d_in[2];
  const float* qla = (const float*)d_in[3];
  const float* qlb = (const float*)d_in[4];
  const float* kw  = (const float*)d_in[5];
  const float* kb  = (const float*)d_in[6];
  const float* kla = (const float*)d_in[7];
  const float* klb = (const float*)d_in[8];
  const float* vw  = (const float*)d_in[9];
  const float* vb  = (const float*)d_in[10];
  const float* vla = (const float*)d_in[11];
  const float* vlb = (const float*)d_in[12];
  const float* ow  = (const float*)d_in[13];
  const float* ob  = (const float*)d_in[14];
  const float* ola = (const float*)d_in[15];
  const float* olb = (const float*)d_in[16];

  short* xb   = (short*)d_ws;                         // 4096*1024 bf16 (reused as ctx)
  short* wb   = xb + (size_t)4096 * 1024;             // 4*1024*1024 bf16
  short* qbuf = wb + (size_t)4 * 1024 * 1024;         // 64*1024*64 each
  short* kbuf = qbuf + (size_t)4194304;
  short* vtb  = kbuf + (size_t)4194304;               // total 40 MB

  prep_kernel<<<8192, 256, 0, stream>>>(x, xb, qw, kw, vw, ow,
                                        qlb, klb, vlb, olb,
                                        qla, kla, vla, ola, wb);
  gemm_qkv<<<256, 512, 0, stream>>>(xb, wb, qb, kb, vb, qbuf, kbuf, vtb);
  attn_kernel<<<dim3(64, 4), 512, 0, stream>>>(qbuf, kbuf, vtb, xb);
  gemm_o<<<256, 256, 0, stream>>>(xb, wb + (size_t)3 * 1024 * 1024, ob, (float*)d_out);
}

// Round 21
// 122.380 us; speedup vs baseline: 1.0018x; 1.0018x over previous
//
#include <hip/hip_runtime.h>
#include <cstdint>

// ---------------------------------------------------------------------------
// LoRA MHA: B=4,S=1024,E=1024,H=16,D=64,R=16.  bf16 MFMA, fp32 accum.
// LoRA folded into the weights: W' = W + B@A (scale=1).
// R21 (FINAL): revert to R19 exactly — measured session best (121.46us).
//   prep: fused cast+fold (8192 blocks)
//   gemm_qkv: 256x192 8-phase counted-vmcnt, grid 256 (100% fill), XCD swz
//   attn: 8-wave swapped-32x32, 3-buffer counted-vmcnt ring, T12/T13 softmax
//   gemm_o: 128^2 depth-2 counted-vmcnt (p3), XCD remap
// R20's 2-tile unroll regressed (vmcnt(0) drains the standing lead) — dropped.
// ---------------------------------------------------------------------------

typedef __attribute__((ext_vector_type(8))) short bf16x8;
typedef __attribute__((ext_vector_type(4))) float f32x4;
typedef __attribute__((ext_vector_type(16))) float f32x16;
typedef __attribute__((ext_vector_type(4))) unsigned short u16x4;
typedef __attribute__((ext_vector_type(4))) unsigned int u32x4;

__device__ __forceinline__ short f2bf(float f) {
  unsigned u = __builtin_bit_cast(unsigned, f);
  u += 0x7FFFu + ((u >> 16) & 1u);          // RNE
  return (short)(u >> 16);
}

typedef __attribute__((address_space(1))) const unsigned int as1_uint;
typedef __attribute__((address_space(3))) unsigned int as3_uint;

__device__ __forceinline__ void gload_lds16(const short* g, const short* l) {
  __builtin_amdgcn_global_load_lds((as1_uint*)g,
      (as3_uint*)(unsigned int)(uintptr_t)l, 16, 0, 0);
}

__device__ __forceinline__ unsigned cvtpk(float lo, float hi) {
  unsigned r;
  asm("v_cvt_pk_bf16_f32 %0, %1, %2" : "=v"(r) : "v"(lo), "v"(hi));
  return r;
}
__device__ __forceinline__ void plswap(unsigned &a, unsigned &b) {
  asm("v_permlane32_swap_b32 %0, %1" : "+v"(a), "+v"(b));
}

__device__ __forceinline__ void build_pfrag(const f32x16 &s, bf16x8 &f0, bf16x8 &f1) {
  unsigned x0 = cvtpk(s[0], s[1]),  x1 = cvtpk(s[2], s[3]);
  unsigned x2 = cvtpk(s[4], s[5]),  x3 = cvtpk(s[6], s[7]);
  plswap(x0, x2); plswap(x1, x3);
  unsigned y0 = cvtpk(s[8], s[9]),  y1 = cvtpk(s[10], s[11]);
  unsigned y2 = cvtpk(s[12], s[13]), y3 = cvtpk(s[14], s[15]);
  plswap(y0, y2); plswap(y1, y3);
  u32x4 a = {x0, x1, x2, x3}, b = {y0, y1, y2, y3};
  f0 = __builtin_bit_cast(bf16x8, a);
  f1 = __builtin_bit_cast(bf16x8, b);
}

// ---------------------------------------------------------------------------
// Kernel 1: fused prep.  Blocks [0,4096): cast x fp32 -> bf16 [4096][1024].
// Blocks [4096,8192): fold LoRA, W'[p] = W_p + B_p@A_p (fp32 -> bf16).
// ---------------------------------------------------------------------------
__global__ void prep_kernel(const float* __restrict__ x, short* __restrict__ xb,
                            const float* __restrict__ wq, const float* __restrict__ wk,
                            const float* __restrict__ wv, const float* __restrict__ wo,
                            const float* __restrict__ bq, const float* __restrict__ bk,
                            const float* __restrict__ bv, const float* __restrict__ bo,
                            const float* __restrict__ aq, const float* __restrict__ ak,
                            const float* __restrict__ av, const float* __restrict__ ao,
                            short* __restrict__ wbo) {
  const int b = blockIdx.x;
  if (b < 4096) {
    const int idx = b * 256 + threadIdx.x;
    f32x4 v = ((const f32x4*)x)[idx];
    u16x4 o;
    o[0] = (unsigned short)f2bf(v[0]);
    o[1] = (unsigned short)f2bf(v[1]);
    o[2] = (unsigned short)f2bf(v[2]);
    o[3] = (unsigned short)f2bf(v[3]);
    ((u16x4*)xb)[idx] = o;
  } else {
    const int bb = b - 4096;
    const int p = bb >> 10;
    const float* W  = (p == 0) ? wq : (p == 1) ? wk : (p == 2) ? wv : wo;
    const float* Bm = (p == 0) ? bq : (p == 1) ? bk : (p == 2) ? bv : bo;
    const float* A  = (p == 0) ? aq : (p == 1) ? ak : (p == 2) ? av : ao;
    const int idx = (bb & 1023) * 256 + threadIdx.x;
    const int n = idx >> 8;
    const int e4 = idx & 255;
    f32x4 acc = ((const f32x4*)(W + (size_t)n * 1024))[e4];
    const float* br = Bm + n * 16;
    #pragma unroll
    for (int r = 0; r < 16; ++r) {
      const f32x4 a4 = ((const f32x4*)(A + (size_t)r * 1024))[e4];
      const float bl = br[r];
      acc[0] += bl * a4[0];
      acc[1] += bl * a4[1];
      acc[2] += bl * a4[2];
      acc[3] += bl * a4[3];
    }
    u16x4 o;
    o[0] = (unsigned short)f2bf(acc[0]);
    o[1] = (unsigned short)f2bf(acc[1]);
    o[2] = (unsigned short)f2bf(acc[2]);
    o[3] = (unsigned short)f2bf(acc[3]);
    *(u16x4*)(wbo + (size_t)p * 1048576 + (size_t)idx * 4) = o;
  }
}

// ---------------------------------------------------------------------------
// Kernel 2: merged q/k/v projection, 256x192 tile, 8 waves (2M x 4N),
// 8-phase counted-vmcnt schedule.  Grid 256 = 16 brow x 16 bcol (100% CU
// fill), XCD swizzle (2 brows x 16 bcols per XCD).
// LDS: A 2buf x 2half x [128][64] = 64 KB ; B 2buf x [192][64] = 48 KB.
// ---------------------------------------------------------------------------
__global__ __launch_bounds__(512, 1)
void gemm_qkv(const short* __restrict__ xb, const short* __restrict__ wb,
              const float* __restrict__ biasq, const float* __restrict__ biask,
              const float* __restrict__ biasv,
              short* __restrict__ qbuf, short* __restrict__ kbuf, short* __restrict__ vtb) {
  __shared__ short Ah[2][2][8192];     // [buf][half][128 rows * 64 cols]
  __shared__ short Bf[2][12288];       // [buf][192 rows * 64 cols]
  const int wg = blockIdx.x;                    // 0..255
  const int swz = (wg & 7) * 32 + (wg >> 3);    // XCD owns 2 brows x 16 bcols
  const int brow = swz >> 4, bcol = swz & 15;
  const int tid = threadIdx.x;
  const int wid = tid >> 6, lane = tid & 63;
  const int wr = wid >> 2, wc = wid & 3;        // 2M x 4N wave grid
  const int lrow = lane & 15, lk = lane >> 4;
  const int sl8 = (tid & 7) ^ ((tid >> 3) & 7); // inverse-swizzled source slot

  const short* Asrc = xb + (size_t)brow * 256 * 1024;
  const short* Bsrc = wb + (size_t)bcol * 192 * 1024;

#define STAGE_A(hf, kt, buf)                                                   \
  { _Pragma("unroll")                                                          \
    for (int i = 0; i < 2; ++i) {                                              \
      const int row = (hf) * 128 + i * 64 + (tid >> 3);                        \
      gload_lds16(Asrc + (size_t)row * 1024 + (kt) * 64 + sl8 * 8,             \
                  Ah[buf][hf] + (i * 64 + wid * 8) * 64);                      \
    } }
#define STAGE_B(ch, kt, buf)                                                   \
  {                                                                            \
    const int row = (ch) * 64 + (tid >> 3);                                    \
    gload_lds16(Bsrc + (size_t)row * 1024 + (kt) * 64 + sl8 * 8,               \
                Bf[buf] + (ch) * 4096 + tid * 8);                              \
  }

  const f32x4 fz = {0.f, 0.f, 0.f, 0.f};
  f32x4 acc[8][3];
  #pragma unroll
  for (int a = 0; a < 8; ++a)
    #pragma unroll
    for (int b = 0; b < 3; ++b) acc[a][b] = fz;

  STAGE_A(0, 0, 0)
  STAGE_A(1, 0, 0)
  STAGE_B(0, 0, 0) STAGE_B(1, 0, 0) STAGE_B(2, 0, 0)
  STAGE_B(0, 1, 1) STAGE_B(1, 1, 1) STAGE_B(2, 1, 1)
  asm volatile("s_waitcnt vmcnt(3)" ::: "memory");
  __builtin_amdgcn_s_barrier();

  for (int t = 0; t < 16; ++t) {
    const int cur = t & 1;
    bf16x8 bfr[3][2];
    #pragma unroll
    for (int q = 0; q < 4; ++q) {
      if (q == 0) {
        #pragma unroll
        for (int nj = 0; nj < 3; ++nj) {
          const int rr = wc * 48 + nj * 16 + lrow;
          #pragma unroll
          for (int kc = 0; kc < 2; ++kc)
            bfr[nj][kc] = *(const bf16x8*)(&Bf[cur][rr * 64 + (((kc * 4 + lk) ^ (rr & 7)) * 8)]);
        }
      }
      bf16x8 afr[2][2];
      #pragma unroll
      for (int m2 = 0; m2 < 2; ++m2) {
        const int rr = q * 32 + m2 * 16 + lrow;
        #pragma unroll
        for (int kc = 0; kc < 2; ++kc)
          afr[m2][kc] = *(const bf16x8*)(&Ah[cur][wr][rr * 64 + (((kc * 4 + lk) ^ (rr & 7)) * 8)]);
      }
      if (q == 0)      { if (t + 1 < 16) STAGE_A(0, t + 1, cur ^ 1) }
      else if (q == 1) { if (t + 1 < 16) STAGE_A(1, t + 1, cur ^ 1) }
      else if (q == 2) { if (t + 2 < 16) { STAGE_B(0, t + 2, cur) STAGE_B(1, t + 2, cur) } }
      else             { if (t + 2 < 16) STAGE_B(2, t + 2, cur) }

      if (q == 0) asm volatile("s_waitcnt lgkmcnt(6)" ::: "memory");
      __builtin_amdgcn_s_barrier();
      asm volatile("s_waitcnt lgkmcnt(0)" ::: "memory");
      __builtin_amdgcn_s_setprio(1);
      #pragma unroll
      for (int kc = 0; kc < 2; ++kc)
        #pragma unroll
        for (int m2 = 0; m2 < 2; ++m2)
          #pragma unroll
          for (int nj = 0; nj < 3; ++nj)
            acc[q * 2 + m2][nj] = __builtin_amdgcn_mfma_f32_16x16x32_bf16(
                afr[m2][kc], bfr[nj][kc], acc[q * 2 + m2][nj], 0, 0, 0);
      __builtin_amdgcn_s_setprio(0);
      if (q == 3) {
        if (t < 14) asm volatile("s_waitcnt vmcnt(3)" ::: "memory");
        else        asm volatile("s_waitcnt vmcnt(0)" ::: "memory");
      }
      __builtin_amdgcn_s_barrier();
    }
  }
#undef STAGE_A
#undef STAGE_B

  const float SCALE = 0.18033688f;   // log2(e)/8 folded into q
  #pragma unroll
  for (int mi = 0; mi < 8; ++mi) {
    #pragma unroll
    for (int r = 0; r < 4; ++r) {
      const int gr = brow * 256 + wr * 128 + mi * 16 + lk * 4 + r;   // C/D row
      const int bb = gr >> 10, s = gr & 1023;
      #pragma unroll
      for (int nj = 0; nj < 3; ++nj) {
        const int gc = bcol * 192 + wc * 48 + nj * 16 + lrow;        // 0..3071
        const int p = gc >> 10, pc = gc & 1023;
        const float bv = ((p == 0) ? biasq : (p == 1) ? biask : biasv)[pc];
        const float v = (acc[mi][nj][r] + bv) * ((p == 0) ? SCALE : 1.0f);
        const int h = pc >> 6, d = pc & 63;
        const int bh = bb * 16 + h;
        if (p == 2)
          vtb[((size_t)bh * 64 + d) * 1024 + s] = f2bf(v);
        else
          ((p == 0) ? qbuf : kbuf)[((size_t)bh * 1024 + s) * 64 + d] = f2bf(v);
      }
    }
  }
}

// ---------------------------------------------------------------------------
// Kernel 3: flash attention, swapped 32x32 MFMA form.
// 8-wave blocks (512 thr, 256 q-rows), grid (64 bh, 4 qt) = 256 blocks.
// 3-buffer LDS ring + counted vmcnt (T4): per tile {STAGE(tt+1)->(tt+1)%3;
// vmcnt(2); lgkmcnt(0); barrier; compute buf tt%3}.
// ---------------------------------------------------------------------------
__global__ __launch_bounds__(512)
void attn_kernel(const short* __restrict__ qbuf, const short* __restrict__ kbuf,
                 const short* __restrict__ vtb, short* __restrict__ cb) {
  __shared__ short Ks[3][64 * 64];
  __shared__ short Vs[3][64 * 64];
  const int bh = blockIdx.x, qt = blockIdx.y;
  const int tid = threadIdx.x, w = tid >> 6, lane = tid & 63;
  const int l31 = lane & 31, hi = lane >> 5;
  const int srow = lane >> 3, sphys = lane & 7;
  const short* Qp = qbuf + (size_t)bh * 65536;
  const short* Kp = kbuf + (size_t)bh * 65536;
  const short* Vp = vtb + (size_t)bh * 65536;
  const int q0 = qt * 256 + w * 32;

  bf16x8 bq[4];
  #pragma unroll
  for (int kc = 0; kc < 4; ++kc)
    bq[kc] = *(const bf16x8*)(Qp + (size_t)(q0 + l31) * 64 + kc * 16 + hi * 8);

  const f32x16 fz16 = {0.f,0.f,0.f,0.f,0.f,0.f,0.f,0.f,0.f,0.f,0.f,0.f,0.f,0.f,0.f,0.f};
  float m_run = -1e30f, l_run = 0.f;
  f32x16 acc0 = fz16, acc1 = fz16;

  #define STAGE_KV(buf, tt)                                                  \
    {                                                                        \
      const int t0s = (tt) * 64;                                             \
      const int row = w * 8 + srow;                                          \
      const int sl = sphys ^ (row & 7);                                      \
      gload_lds16(Kp + (size_t)(t0s + row) * 64 + sl * 8, Ks[buf] + w * 512); \
      gload_lds16(Vp + (size_t)row * 1024 + t0s + sl * 8, Vs[buf] + w * 512); \
    }

  STAGE_KV(0, 0);

  int cur = 0, nxt = 1;
  for (int tt = 0; tt < 16; ++tt) {
    if (tt < 15) {
      STAGE_KV(nxt, tt + 1);
      asm volatile("s_waitcnt vmcnt(2)" ::: "memory");   // tile tt landed (mine)
    } else {
      asm volatile("s_waitcnt vmcnt(0)" ::: "memory");
    }
    asm volatile("s_waitcnt lgkmcnt(0)" ::: "memory");   // my prev reads retired
    __builtin_amdgcn_s_barrier();                        // all waves: tile tt ready

    // ---- S^T = K · Q^T ----
    f32x16 s0 = fz16, s1 = fz16;
    __builtin_amdgcn_s_setprio(1);
    #pragma unroll
    for (int kc = 0; kc < 4; ++kc) {
      const int slot = (kc * 2 + hi) ^ (l31 & 7);
      const bf16x8 ak0 = *(const bf16x8*)(Ks[cur] + l31 * 64 + slot * 8);
      const bf16x8 ak1 = *(const bf16x8*)(Ks[cur] + (32 + l31) * 64 + slot * 8);
      s0 = __builtin_amdgcn_mfma_f32_32x32x16_bf16(ak0, bq[kc], s0, 0, 0, 0);
      s1 = __builtin_amdgcn_mfma_f32_32x32x16_bf16(ak1, bq[kc], s1, 0, 0, 0);
    }
    __builtin_amdgcn_s_setprio(0);

    // ---- max: pairwise tree ----
    float t16[16];
    #pragma unroll
    for (int r = 0; r < 8; ++r) t16[r] = fmaxf(s0[2 * r], s0[2 * r + 1]);
    #pragma unroll
    for (int r = 0; r < 8; ++r) t16[8 + r] = fmaxf(s1[2 * r], s1[2 * r + 1]);
    #pragma unroll
    for (int r = 0; r < 8; ++r) t16[r] = fmaxf(t16[r], t16[r + 8]);
    #pragma unroll
    for (int r = 0; r < 4; ++r) t16[r] = fmaxf(t16[r], t16[r + 4]);
    float tm = fmaxf(fmaxf(t16[0], t16[1]), fmaxf(t16[2], t16[3]));
    tm = fmaxf(tm, __shfl_xor(tm, 32, 64));

    // ---- defer-max (T13) ----
    if (__any(tm - m_run > 8.0f)) {
      const float mn = fmaxf(m_run, tm);
      const float alpha = exp2f(m_run - mn);
      m_run = mn;
      l_run *= alpha;
      #pragma unroll
      for (int r = 0; r < 16; ++r) { acc0[r] *= alpha; acc1[r] *= alpha; }
    }

    // ---- P = 2^(S - m), sum via pairwise tree ----
    float a16[16];
    #pragma unroll
    for (int r = 0; r < 16; ++r) { s0[r] = exp2f(s0[r] - m_run); }
    #pragma unroll
    for (int r = 0; r < 16; ++r) { s1[r] = exp2f(s1[r] - m_run); }
    #pragma unroll
    for (int r = 0; r < 8; ++r) a16[r] = s0[2 * r] + s0[2 * r + 1];
    #pragma unroll
    for (int r = 0; r < 8; ++r) a16[8 + r] = s1[2 * r] + s1[2 * r + 1];
    #pragma unroll
    for (int r = 0; r < 8; ++r) a16[r] += a16[r + 8];
    #pragma unroll
    for (int r = 0; r < 4; ++r) a16[r] += a16[r + 4];
    float rs = (a16[0] + a16[1]) + (a16[2] + a16[3]);
    rs += __shfl_xor(rs, 32, 64);
    l_run += rs;

    // ---- P^T fragments (in-register, T12) ----
    bf16x8 pf[4];
    build_pfrag(s0, pf[0], pf[1]);
    build_pfrag(s1, pf[2], pf[3]);

    // ---- O^T += V^T · P^T ----
    __builtin_amdgcn_s_setprio(1);
    #pragma unroll
    for (int kc4 = 0; kc4 < 4; ++kc4) {
      const int slot = (kc4 * 2 + hi) ^ (l31 & 7);
      const bf16x8 av0 = *(const bf16x8*)(Vs[cur] + l31 * 64 + slot * 8);
      const bf16x8 av1 = *(const bf16x8*)(Vs[cur] + (32 + l31) * 64 + slot * 8);
      acc0 = __builtin_amdgcn_mfma_f32_32x32x16_bf16(av0, pf[kc4], acc0, 0, 0, 0);
      acc1 = __builtin_amdgcn_mfma_f32_32x32x16_bf16(av1, pf[kc4], acc1, 0, 0, 0);
    }
    __builtin_amdgcn_s_setprio(0);

    cur = (cur == 2) ? 0 : (cur + 1);
    nxt = (nxt == 2) ? 0 : (nxt + 1);
  }

  const int bb = bh >> 4, h = bh & 15;
  const int s = q0 + l31;
  short* crow = cb + (size_t)(bb * 1024 + s) * 1024 + h * 64;
  const float inv = 1.f / l_run;
  #pragma unroll
  for (int rp = 0; rp < 8; ++rp) {
    const int r = rp * 2;
    const int d = (r & 3) + 8 * (r >> 2) + 4 * hi;
    const unsigned p0 = (unsigned)(unsigned short)f2bf(acc0[r] * inv)
                      | ((unsigned)(unsigned short)f2bf(acc0[r + 1] * inv) << 16);
    const unsigned p1 = (unsigned)(unsigned short)f2bf(acc1[r] * inv)
                      | ((unsigned)(unsigned short)f2bf(acc1[r + 1] * inv) << 16);
    *(unsigned*)(crow + d) = p0;
    *(unsigned*)(crow + 32 + d) = p1;
  }
  #undef STAGE_KV
}

// ---------------------------------------------------------------------------
// GEMM core, depth-2 counted-vmcnt pipeline (gemm_o).
// ---------------------------------------------------------------------------
__device__ __forceinline__ void gemm_core_p3(const short* __restrict__ xrow,
                                             const short* __restrict__ wrow,
                                             short (&As)[3][8192], short (&Bs)[3][8192],
                                             f32x4 (&acc)[4][4]) {
  const int tid = threadIdx.x;
  const int wv = tid >> 6, lane = tid & 63;
  const int wr = wv >> 1, wc = wv & 1;
  const int lrow = lane & 15, lk = lane >> 4;
  const int srow = lane >> 3, sphys = lane & 7;

#define STAGE_G(buf, kt)                                                       \
  {                                                                            \
    _Pragma("unroll")                                                          \
    for (int i = 0; i < 4; ++i) {                                              \
      const int ch = i * 4 + wv;                                               \
      const int row = ch * 8 + srow;                                           \
      const int sl = sphys ^ (row & 7);                                        \
      gload_lds16(xrow + (size_t)row * 1024 + (kt) * 64 + sl * 8, As[buf] + ch * 512); \
      gload_lds16(wrow + (size_t)row * 1024 + (kt) * 64 + sl * 8, Bs[buf] + ch * 512); \
    }                                                                          \
  }

  STAGE_G(0, 0);
  STAGE_G(1, 1);
  int cur = 0;
  for (int kt = 0; kt < 16; ++kt) {
    if (kt < 14) {
      const int nb = (cur == 0) ? 2 : (cur - 1);   // (kt+2)%3
      STAGE_G(nb, kt + 2);
      asm volatile("s_waitcnt vmcnt(16)" ::: "memory");
    } else if (kt == 14) {
      asm volatile("s_waitcnt vmcnt(8)" ::: "memory");
    } else {
      asm volatile("s_waitcnt vmcnt(0)" ::: "memory");
    }
    __builtin_amdgcn_s_barrier();

    #pragma unroll
    for (int kc = 0; kc < 2; ++kc) {
      bf16x8 af[4], bw[4];
      #pragma unroll
      for (int mi = 0; mi < 4; ++mi) {
        const int row = wr * 64 + mi * 16 + lrow;
        const int slot = (kc * 4 + lk) ^ (row & 7);
        af[mi] = *(const bf16x8*)(As[cur] + row * 64 + slot * 8);
      }
      #pragma unroll
      for (int nj = 0; nj < 4; ++nj) {
        const int row = wc * 64 + nj * 16 + lrow;
        const int slot = (kc * 4 + lk) ^ (row & 7);
        bw[nj] = *(const bf16x8*)(Bs[cur] + row * 64 + slot * 8);
      }
      __builtin_amdgcn_s_setprio(1);
      #pragma unroll
      for (int mi = 0; mi < 4; ++mi)
        #pragma unroll
        for (int nj = 0; nj < 4; ++nj)
          acc[mi][nj] = __builtin_amdgcn_mfma_f32_16x16x32_bf16(af[mi], bw[nj], acc[mi][nj], 0, 0, 0);
      __builtin_amdgcn_s_setprio(0);
    }

    asm volatile("s_waitcnt lgkmcnt(0)" ::: "memory");
    __builtin_amdgcn_s_barrier();
    cur = (cur == 2) ? 0 : (cur + 1);
  }
#undef STAGE_G
}

// ---------------------------------------------------------------------------
// Kernel 4: o-projection -> fp32 d_out (p3 core).  1-D grid 256; XCD remap:
// xcd = wg&7 owns brows [4*xcd, 4*xcd+4) x all 8 bcols.
// ---------------------------------------------------------------------------
__global__ __launch_bounds__(256)
void gemm_o(const short* __restrict__ cb, const short* __restrict__ wo,
            const float* __restrict__ biaso, float* __restrict__ out) {
  __shared__ short As[3][8192];
  __shared__ short Bs[3][8192];
  const int wg = blockIdx.x;              // 0..255
  const int xcd = wg & 7, ix = wg >> 3;   // 32 blocks per XCD
  const int brow = xcd * 4 + (ix & 3);    // 4 brows per XCD
  const int bcol = ix >> 2;               // all 8 bcols
  const f32x4 fz = {0.f, 0.f, 0.f, 0.f};
  f32x4 acc[4][4];
  #pragma unroll
  for (int a = 0; a < 4; ++a)
    #pragma unroll
    for (int b = 0; b < 4; ++b) acc[a][b] = fz;

  gemm_core_p3(cb + (size_t)brow * 128 * 1024, wo + (size_t)bcol * 128 * 1024,
               As, Bs, acc);

  const int tid = threadIdx.x;
  const int wv = tid >> 6, lane = tid & 63;
  const int wr = wv >> 1, wc = wv & 1;
  const int lrow = lane & 15, lk = lane >> 4;
  float bcv[4];
  #pragma unroll
  for (int nj = 0; nj < 4; ++nj)
    bcv[nj] = biaso[bcol * 128 + wc * 64 + nj * 16 + lrow];

  #pragma unroll
  for (int mi = 0; mi < 4; ++mi) {
    #pragma unroll
    for (int r = 0; r < 4; ++r) {
      const int gr = brow * 128 + wr * 64 + mi * 16 + lk * 4 + r;
      #pragma unroll
      for (int nj = 0; nj < 4; ++nj) {
        const int gc = bcol * 128 + wc * 64 + nj * 16 + lrow;
        out[(size_t)gr * 1024 + gc] = acc[mi][nj][r] + bcv[nj];
      }
    }
  }
}

// ---------------------------------------------------------------------------
extern "C" void kernel_launch(void* const* d_in, const int* in_sizes, int n_in,
                              void* d_out, int out_size, void* d_ws, size_t ws_size,
                              hipStream_t stream) {
  (void)in_sizes; (void)n_in; (void)out_size; (void)ws_size;
  const float* x   = (const float*)d_in[0];
  const float* qw  = (const float*)d_in[1];
  const float* qb  = (const float*)d_in[2];
  const float* qla = (const float*)d_in[3];
  const float* qlb = (const float*)d_in[4];
  const float* kw  = (const float*)d_in[5];
  const float* kb  = (const float*)d_in[6];
  const float* kla = (const float*)d_in[7];
  const float* klb = (const float*)d_in[8];
  const float* vw  = (const float*)d_in[9];
  const float* vb  = (const float*)d_in[10];
  const float* vla = (const float*)d_in[11];
  const float* vlb = (const float*)d_in[12];
  const float* ow  = (const float*)d_in[13];
  const float* ob  = (const float*)d_in[14];
  const float* ola = (const float*)d_in[15];
  const float* olb = (const float*)d_in[16];

  short* xb   = (short*)d_ws;                         // 4096*1024 bf16 (reused as ctx)
  short* wb   = xb + (size_t)4096 * 1024;             // 4*1024*1024 bf16
  short* qbuf = wb + (size_t)4 * 1024 * 1024;         // 64*1024*64 each
  short* kbuf = qbuf + (size_t)4194304;
  short* vtb  = kbuf + (size_t)4194304;               // total 40 MB

  prep_kernel<<<8192, 256, 0, stream>>>(x, xb, qw, kw, vw, ow,
                                        qlb, klb, vlb, olb,
                                        qla, kla, vla, ola, wb);
  gemm_qkv<<<256, 512, 0, stream>>>(xb, wb, qb, kb, vb, qbuf, kbuf, vtb);
  attn_kernel<<<dim3(64, 4), 512, 0, stream>>>(qbuf, kbuf, vtb, xb);
  gemm_o<<<256, 256, 0, stream>>>(xb, wb + (size_t)3 * 1024 * 1024, ob, (float*)d_out);
}